// Round 6
// baseline (169.481 us; speedup 1.0000x reference)
//
#include <hip/hip_runtime.h>

// SoftDTW: B=64, M=N=512, gamma=0.01, P=2.
// Chunked-skew wavefront, 8-wave edition (2 waves/SIMD for latency hiding):
//   - 64 blocks (one per batch), 512 threads = 8 waves.
//   - Wave w owns cols [64w, 64w+63]; lane l owns single col j = 64w + l.
//   - D=32 diagonals per macro-step; skew: wave w does chunk c = s - w.
//   - Left-neighbor via DPP wave_shr:1 (VALU); boundary via 128-deep LDS ring.
//   - Cost window dw[t] precomputed per chunk with border clamp folded in.
//   - NUMERICS: exp2 args computed as (m - med) * K (sub-then-mul), which is
//     guaranteed <= 0 in fp32 (rounding is monotone). The previous
//     fmaf(med, -K, m*K) form could leave a +ulp residual (~4e28 at 1e33
//     operand scale) -> exp2(+huge) = inf -> NaN cascade. Do NOT "optimize"
//     back to fma here.

#define BIGF 1e30f

__device__ __forceinline__ float dpp_shr1(float v) {
    int i = __float_as_int(v);
    int r = __builtin_amdgcn_update_dpp(i, i, 0x138 /*WAVE_SHR1*/, 0xF, 0xF, false);
    return __int_as_float(r);
}
__device__ __forceinline__ float rdlane(float v, int l) {
    return __int_as_float(__builtin_amdgcn_readlane(__float_as_int(v), l));
}

__global__ __launch_bounds__(512) void softdtw_kernel(
    const float* __restrict__ x, const float* __restrict__ y,
    float* __restrict__ out)
{
    constexpr int N = 512;
    constexpr int D = 32;                 // diagonals per chunk
    constexpr int NC = 32;                // chunks (diags 0..1023; 1023 harmless)
    constexpr int W = 8;                  // waves per block
    constexpr int NSTEPS = NC + W - 1;    // 39
    constexpr int PAD = 64;

    const int b = blockIdx.x;
    const int tid = threadIdx.x;
    const int w = tid >> 6;
    const int lane = tid & 63;

    __shared__ float ylds[N + 2 * PAD];   // index PAD + i, i in [-64, N+63]
    __shared__ float bnd[W][128];         // per-wave boundary ring, slot = d & 127

    const int j = 64 * w + lane;          // owned column
    const float xj = x[b * N + j];
    for (int k = tid; k < N + 2 * PAD; k += 512) {
        int i = k - PAD;
        ylds[k] = ((unsigned)i < (unsigned)N) ? y[b * N + i] : 0.0f;
    }
    for (int k = tid; k < W * 128; k += 512) ((float*)bnd)[k] = BIGF;
    __syncthreads();

    const float K = 144.26950408889634f;   // 100 * log2(e)
    const float C = 0.006931471805599453f; // 0.01 * ln(2)
    const bool is0 = (lane == 0);

    float r1 = BIGF, r2 = BIGF;            // own col R at diag d-1 / d-2
    float edge_prev = BIGF;                // boundary value, diag d-2
    float sh_prev = BIGF;                  // dpp_shr1(r1) from previous diagonal

    for (int s = 0; s < NSTEPS; ++s) {
        const int c = s - w;
        if (c >= 0 && c < NC) {
            const int d0 = D * c;

            // ---- per-chunk preamble (all off the dependent chain) ----
            const int iA0 = d0 - j;        // row at t=0
            int base = iA0 < -PAD ? -PAD : (iA0 > N + PAD - D ? N + PAD - D : iA0);
            // clamp fires only when ALL cells in chunk are out-of-range
            float dw[D];
#pragma unroll
            for (int t = 0; t < D; ++t) {
                float diff = xj - ylds[PAD + base + t];
                dw[t] = ((unsigned)(iA0 + t) < (unsigned)N) ? diff * diff : BIGF;
            }

            float pre;                     // lane l = boundary value at diag d0-2+l
            if (w == 0) {
                pre = (c == 0 && lane == 0) ? 0.0f : BIGF;  // R[-1,-1]=0 seed
            } else {
                pre = bnd[w - 1][(unsigned)(d0 - 2 + lane) & 127u];
            }
            edge_prev = rdlane(pre, 0);

            // ---- dependent wavefront loop ----
#pragma unroll
            for (int t = 0; t < D; ++t) {
                const float sh1 = dpp_shr1(r1);           // left col, diag d-1
                const float rl_edge = rdlane(pre, t + 1); // boundary, diag d-1
                const float rl = is0 ? rl_edge : sh1;     // R[i,   j-1]
                const float rd = is0 ? edge_prev : sh_prev; // R[i-1, j-1]
                // ru = R[i-1, j] = r1

                const float m   = fminf(rd, fminf(r1, rl));
                const float med = __builtin_amdgcn_fmed3f(rd, r1, rl);
                const float mx  = fmaxf(rd, fmaxf(r1, rl));
                // (m - med) <= 0 and (m - mx) <= 0 guaranteed in fp32:
                // sub-then-mul, NOT fma (see header comment).
                const float e1  = __builtin_amdgcn_exp2f((m - med) * K);
                const float e2  = __builtin_amdgcn_exp2f((m - mx) * K);
                const float lg  = __builtin_amdgcn_logf((1.0f + e1) + e2);
                const float v   = fmaf(-C, lg, dw[t] + m);

                if (lane == 63) bnd[w][(d0 + t) & 127] = v;  // publish strip edge

                r2 = r1; r1 = v;
                edge_prev = rl_edge;
                sh_prev = sh1;
            }
        }
        __syncthreads();
    }

    // col 511 = (wave 7, lane 63); diag 1022 value lands in r1, rotated to r2 at t=31
    if (tid == 511) out[b] = r2;
}

extern "C" void kernel_launch(void* const* d_in, const int* in_sizes, int n_in,
                              void* d_out, int out_size, void* d_ws, size_t ws_size,
                              hipStream_t stream) {
    const float* x = (const float*)d_in[0];  // [64, 512]
    const float* y = (const float*)d_in[1];  // [64, 512]
    float* out = (float*)d_out;              // [64]
    softdtw_kernel<<<64, 512, 0, stream>>>(x, y, out);
}

// Round 7
// 169.394 us; speedup vs baseline: 1.0005x; 1.0005x over previous
//
#include <hip/hip_runtime.h>

// SoftDTW: B=64, M=N=512, gamma=0.01, P=2.
// Chunked-skew wavefront, 8-wave edition:
//   - 64 blocks (one per batch), 512 threads = 8 waves (2 per SIMD).
//   - Wave w owns cols [64w, 64w+63]; lane l owns single col j = 64w + l.
//   - D=32 diagonals per macro-step; skew: wave w does chunk c = s - w.
//   - Left-neighbor via DPP wave_shr:1 (VALU); boundary via 128-deep LDS ring.
//   - __launch_bounds__(512, 2): min 2 waves/EU -> up to 256 VGPRs, so the
//     dw[32] cost window stays in REGISTERS. (R5 postmortem: default heuristic
//     allocated 28 VGPRs and sank the preamble into the dependent loop ->
//     ~50 VALU insts/iter instead of ~18.)
//   - sched_barrier(0) separates preamble (all DS loads, one lgkmcnt wait)
//     from the dependent loop (pure VALU/DPP, no memory waits).
//   - NUMERICS: exp2 args computed as (m - med) * K (sub-then-mul), which is
//     guaranteed <= 0 in fp32. fmaf(med, -K, m*K) can leave a +ulp residual
//     (~4e28 at 1e33 operand scale) -> exp2(+huge) = inf -> NaN cascade.
//     Do NOT "optimize" back to fma here.

#define BIGF 1e30f

__device__ __forceinline__ float dpp_shr1(float v) {
    int i = __float_as_int(v);
    int r = __builtin_amdgcn_update_dpp(i, i, 0x138 /*WAVE_SHR1*/, 0xF, 0xF, false);
    return __int_as_float(r);
}
__device__ __forceinline__ float rdlane(float v, int l) {
    return __int_as_float(__builtin_amdgcn_readlane(__float_as_int(v), l));
}

__global__ __launch_bounds__(512, 2) void softdtw_kernel(
    const float* __restrict__ x, const float* __restrict__ y,
    float* __restrict__ out)
{
    constexpr int N = 512;
    constexpr int D = 32;                 // diagonals per chunk
    constexpr int NC = 32;                // chunks (diags 0..1023; 1023 harmless)
    constexpr int W = 8;                  // waves per block
    constexpr int NSTEPS = NC + W - 1;    // 39
    constexpr int PAD = 64;

    const int b = blockIdx.x;
    const int tid = threadIdx.x;
    const int w = tid >> 6;
    const int lane = tid & 63;

    __shared__ float ylds[N + 2 * PAD];   // index PAD + i, i in [-64, N+63]
    __shared__ float bnd[W][128];         // per-wave boundary ring, slot = d & 127

    const int j = 64 * w + lane;          // owned column
    const float xj = x[b * N + j];
    for (int k = tid; k < N + 2 * PAD; k += 512) {
        int i = k - PAD;
        ylds[k] = ((unsigned)i < (unsigned)N) ? y[b * N + i] : 0.0f;
    }
    for (int k = tid; k < W * 128; k += 512) ((float*)bnd)[k] = BIGF;
    __syncthreads();

    const float K = 144.26950408889634f;   // 100 * log2(e)
    const float C = 0.006931471805599453f; // 0.01 * ln(2)
    const bool is0 = (lane == 0);

    float r1 = BIGF, r2 = BIGF;            // own col R at diag d-1 / d-2
    float edge_prev = BIGF;                // boundary value, diag d-2
    float sh_prev = BIGF;                  // dpp_shr1(r1) from previous diagonal

    for (int s = 0; s < NSTEPS; ++s) {
        const int c = s - w;
        if (c >= 0 && c < NC) {
            const int d0 = D * c;

            // ---- per-chunk preamble: all DS traffic happens here ----
            const int iA0 = d0 - j;        // row at t=0
            int base = iA0 < -PAD ? -PAD : (iA0 > N + PAD - D ? N + PAD - D : iA0);
            // clamp fires only when ALL cells in chunk are out-of-range
            float dw[D];
#pragma unroll
            for (int t = 0; t < D; ++t) {
                float diff = xj - ylds[PAD + base + t];
                dw[t] = ((unsigned)(iA0 + t) < (unsigned)N) ? diff * diff : BIGF;
            }

            float pre;                     // lane l = boundary value at diag d0-2+l
            if (w == 0) {
                pre = (c == 0 && lane == 0) ? 0.0f : BIGF;  // R[-1,-1]=0 seed
            } else {
                pre = bnd[w - 1][(unsigned)(d0 - 2 + lane) & 127u];
            }
            edge_prev = rdlane(pre, 0);

            // fence: preamble loads complete here; loop below is memory-free
            __builtin_amdgcn_sched_barrier(0);

            // ---- dependent wavefront loop (pure VALU/DPP + 1 ds_write) ----
#pragma unroll
            for (int t = 0; t < D; ++t) {
                const float sh1 = dpp_shr1(r1);           // left col, diag d-1
                const float rl_edge = rdlane(pre, t + 1); // boundary, diag d-1
                const float rl = is0 ? rl_edge : sh1;     // R[i,   j-1]
                const float rd = is0 ? edge_prev : sh_prev; // R[i-1, j-1]
                // ru = R[i-1, j] = r1

                const float m   = fminf(rd, fminf(r1, rl));
                const float med = __builtin_amdgcn_fmed3f(rd, r1, rl);
                const float mx  = fmaxf(rd, fmaxf(r1, rl));
                // sub-then-mul, NOT fma (see header comment)
                const float e1  = __builtin_amdgcn_exp2f((m - med) * K);
                const float e2  = __builtin_amdgcn_exp2f((m - mx) * K);
                const float lg  = __builtin_amdgcn_logf((1.0f + e1) + e2);
                const float v   = fmaf(-C, lg, dw[t] + m);

                if (lane == 63) bnd[w][(d0 + t) & 127] = v;  // publish strip edge

                r2 = r1; r1 = v;
                edge_prev = rl_edge;
                sh_prev = sh1;
            }
        }
        __syncthreads();
    }

    // col 511 = (wave 7, lane 63); diag 1022 value lands in r1, rotated to r2 at t=31
    if (tid == 511) out[b] = r2;
}

extern "C" void kernel_launch(void* const* d_in, const int* in_sizes, int n_in,
                              void* d_out, int out_size, void* d_ws, size_t ws_size,
                              hipStream_t stream) {
    const float* x = (const float*)d_in[0];  // [64, 512]
    const float* y = (const float*)d_in[1];  // [64, 512]
    float* out = (float*)d_out;              // [64]
    softdtw_kernel<<<64, 512, 0, stream>>>(x, y, out);
}